// Round 3
// baseline (1263.169 us; speedup 1.0000x reference)
//
#include <hip/hip_runtime.h>

typedef __bf16 bf16x8 __attribute__((ext_vector_type(8)));
typedef unsigned short us8 __attribute__((ext_vector_type(8)));
typedef float f32x4 __attribute__((ext_vector_type(4)));

#define NROW 32      // rows per workgroup (160 WGs x 32 = 5120)
#define A_STR 136    // ushort stride per A row: 16B-aligned, 4-dword bank skew
#define NSTEP 119

__device__ __forceinline__ unsigned short f2bf(float f){
  unsigned int x = __builtin_bit_cast(unsigned int, f);
  x += 0x7fffu + ((x >> 16) & 1u);          // RNE
  return (unsigned short)(x >> 16);
}
__device__ __forceinline__ float bf2f(unsigned short s){
  unsigned int x = ((unsigned int)s) << 16;
  return __builtin_bit_cast(float, x);
}
__device__ __forceinline__ float sigm(float x){ return 1.0f/(1.0f + __expf(-x)); }
__device__ __forceinline__ float tanh_(float x){ float e = __expf(2.0f*x); return 1.0f - 2.0f/(e + 1.0f); }

__device__ __forceinline__ f32x4 MFMA(us8 a, us8 b, f32x4 c){
  return __builtin_amdgcn_mfma_f32_16x16x32_bf16(
      __builtin_bit_cast(bf16x8, a), __builtin_bit_cast(bf16x8, b), c, 0, 0, 0);
}

struct SharedMem {
  unsigned short A0[2][NROW*A_STR];   // h0 state, bf16, double buffered
  unsigned short A1[2][NROW*A_STR];   // h1 state, bf16, double buffered
  unsigned short Ax[2][NROW][32];     // x-MFMA A operand: k=0 tgt, 1-4 cov, 5 one, 6.. zero
  unsigned short xw[512*8];           // x-MFMA B operand per gate-col: u,Wc0-3,v,0,0
  float b1[512];                      // bih1+bhh1 per col
  float Wh2f[256];                    // Wh flattened
  float red[NROW][16][2];             // head partial sums
  float we_s[64];
  float be_s[64];
  float bh_s[2];
};

__global__ __launch_bounds__(512)
__attribute__((amdgpu_waves_per_eu(2, 2)))
void deepar_kernel(
    const float* __restrict__ hist, const float* __restrict__ fut,
    const float* __restrict__ We,   const float* __restrict__ be,
    const float* __restrict__ Wih0, const float* __restrict__ Whh0,
    const float* __restrict__ bih0, const float* __restrict__ bhh0,
    const float* __restrict__ Wih1, const float* __restrict__ Whh1,
    const float* __restrict__ bih1, const float* __restrict__ bhh1,
    const float* __restrict__ Wh,   const float* __restrict__ bh,
    float* __restrict__ out)
{
  __shared__ SharedMem S;
  const int tid = threadIdx.x;
  const int wg  = blockIdx.x;
  const int b   = wg / 10;
  const int n0  = (wg % 10) * NROW;
  const int w   = tid >> 6;        // wave 0..7
  const int l   = tid & 63;
  const int gq  = l >> 4;          // k-group 0..3
  const int r   = l & 15;          // row/col within 16-tile

  // ---------------- prologue: zero + param staging ----------------
  {
    us8 z = {0,0,0,0,0,0,0,0};
    us8* pA0 = (us8*)&S.A0[0][0];
    us8* pA1 = (us8*)&S.A1[0][0];
    for (int i = tid; i < 2*NROW*A_STR/8; i += 512){ pA0[i] = z; pA1[i] = z; }
    us8* pAx = (us8*)&S.Ax[0][0][0];
    for (int i = tid; i < 2*NROW*32/8; i += 512) pAx[i] = z;
  }
  if (tid < 64)       S.we_s[tid]       = We[tid];
  else if (tid < 128) S.be_s[tid - 64]  = be[tid - 64];
  else if (tid < 384) S.Wh2f[tid - 128] = Wh[tid - 128];
  else if (tid < 386) S.bh_s[tid - 384] = bh[tid - 384];
  __syncthreads();

  // per-col x weights: u = Wih0[:, :64]@We ; v = Wih0[:, :64]@be + bih0 + bhh0
  {
    const float* wr = Wih0 + tid * 68;
    float u = 0.f, v = 0.f;
    #pragma unroll 8
    for (int e = 0; e < 64; ++e){
      float wv = wr[e];
      u = fmaf(wv, S.we_s[e], u);
      v = fmaf(wv, S.be_s[e], v);
    }
    v += bih0[tid] + bhh0[tid];
    unsigned short* xp = &S.xw[tid * 8];
    xp[0] = f2bf(u);
    xp[1] = f2bf(wr[64]); xp[2] = f2bf(wr[65]); xp[3] = f2bf(wr[66]); xp[4] = f2bf(wr[67]);
    xp[5] = f2bf(v);
    xp[6] = 0; xp[7] = 0;
    S.b1[tid] = bih1[tid] + bhh1[tid];
  }
  // Ax constant-one column (k=5), both buffers
  if (tid < 64){ int row = tid >> 1, bsel = tid & 1; S.Ax[bsel][row][5] = 0x3F80; }
  // stage step-0 scalars: tgt tau=0, cov tau=1 -> Ax[0]
  if (tid < 160){
    int srow, sch, tau;
    if (tid < 32){ srow = tid; sch = 0; tau = 0; }
    else { int k = tid - 32; srow = k >> 2; sch = 1 + (k & 3); tau = 1; }
    const float* p = hist + ((b*96 + tau)*320 + n0 + srow)*5;
    S.Ax[0][srow][sch] = f2bf(p[sch]);
  }

  // register-resident recurrent weights: WB[mat][gate][kblock]
  us8 WB[3][4][4];
  #pragma unroll
  for (int m = 0; m < 3; ++m){
    const float* base = (m == 0) ? Whh0 : (m == 1) ? Wih1 : Whh1;
    #pragma unroll
    for (int g = 0; g < 4; ++g){
      int col = g*128 + w*16 + r;
      #pragma unroll
      for (int q = 0; q < 4; ++q){
        const float* p = base + col*128 + q*32 + gq*8;
        f32x4 x0 = *(const f32x4*)p;
        f32x4 x1 = *(const f32x4*)(p + 4);
        us8 tt;
        tt[0]=f2bf(x0[0]); tt[1]=f2bf(x0[1]); tt[2]=f2bf(x0[2]); tt[3]=f2bf(x0[3]);
        tt[4]=f2bf(x1[0]); tt[5]=f2bf(x1[1]); tt[6]=f2bf(x1[2]); tt[7]=f2bf(x1[3]);
        WB[m][g][q] = tt;
      }
    }
  }

  float c0s[2][4], c1s[2][4];
  #pragma unroll
  for (int rt = 0; rt < 2; ++rt)
    #pragma unroll
    for (int j = 0; j < 4; ++j){ c0s[rt][j] = 0.f; c1s[rt][j] = 0.f; }

  __syncthreads();

  // ---------------- time loop ----------------
  for (int t = 0; t < NSTEP; ++t){
    const int pb = t & 1, nb = pb ^ 1;
    const unsigned short* A0r = S.A0[pb];
    unsigned short*       A0w = S.A0[nb];
    const unsigned short* A1r = S.A1[pb];
    unsigned short*       A1w = S.A1[nb];

    // issue next-step scalar loads FIRST (hide HBM latency under both MFMA phases)
    float stv = 0.f; int sto = -1;
    if (t + 1 < NSTEP && tid < 160){
      int srow, sch, tau;
      if (tid < 32){ srow = tid; sch = 0; tau = t + 1; }
      else { int k = tid - 32; srow = k >> 2; sch = 1 + (k & 3); tau = t + 2; }
      const float* p = (tau < 96) ? (hist + ((b*96 + tau)*320 + n0 + srow)*5)
                                  : (fut  + ((b*24 + (tau - 96))*320 + n0 + srow)*5);
      stv = p[sch];
      sto = nb*NROW*32 + srow*32 + sch;
    }

    // ---- layer 0: gates = x-MFMA + h0 @ Whh0^T ; in-register activations ----
    #pragma unroll
    for (int rt = 0; rt < 2; ++rt){
      const int rbase = rt * 16;
      f32x4 acc[4];
      us8 ax = *(const us8*)&S.Ax[pb][rbase + r][gq*8];
      #pragma unroll
      for (int g = 0; g < 4; ++g){
        us8 bx = *(const us8*)&S.xw[(g*128 + w*16 + r)*8];
        f32x4 z = {0.f,0.f,0.f,0.f};
        acc[g] = MFMA(ax, bx, z);
      }
      #pragma unroll
      for (int q = 0; q < 4; ++q){
        us8 a = *(const us8*)&A0r[(rbase + r)*A_STR + q*32 + gq*8];
        #pragma unroll
        for (int g = 0; g < 4; ++g) acc[g] = MFMA(a, WB[0][g][q], acc[g]);
      }
      #pragma unroll
      for (int j = 0; j < 4; ++j){
        float c = fmaf(sigm(acc[1][j]), c0s[rt][j], sigm(acc[0][j]) * tanh_(acc[2][j]));
        c0s[rt][j] = c;
        float h = sigm(acc[3][j]) * tanh_(c);
        A0w[(rbase + gq*4 + j)*A_STR + w*16 + r] = f2bf(h);
      }
    }
    __syncthreads();   // B1: new h0 visible

    // ---- layer 1: gates = b1 + h0new @ Wih1^T + h1 @ Whh1^T ----
    float b1g[4];
    #pragma unroll
    for (int g = 0; g < 4; ++g) b1g[g] = S.b1[g*128 + w*16 + r];

    #pragma unroll
    for (int rt = 0; rt < 2; ++rt){
      const int rbase = rt * 16;
      f32x4 acc[4];
      #pragma unroll
      for (int g = 0; g < 4; ++g){ f32x4 iv = {b1g[g],b1g[g],b1g[g],b1g[g]}; acc[g] = iv; }
      #pragma unroll
      for (int q = 0; q < 4; ++q){
        us8 a = *(const us8*)&A0w[(rbase + r)*A_STR + q*32 + gq*8];
        #pragma unroll
        for (int g = 0; g < 4; ++g) acc[g] = MFMA(a, WB[1][g][q], acc[g]);
      }
      #pragma unroll
      for (int q = 0; q < 4; ++q){
        us8 a = *(const us8*)&A1r[(rbase + r)*A_STR + q*32 + gq*8];
        #pragma unroll
        for (int g = 0; g < 4; ++g) acc[g] = MFMA(a, WB[2][g][q], acc[g]);
      }
      #pragma unroll
      for (int j = 0; j < 4; ++j){
        float c = fmaf(sigm(acc[1][j]), c1s[rt][j], sigm(acc[0][j]) * tanh_(acc[2][j]));
        c1s[rt][j] = c;
        float h = sigm(acc[3][j]) * tanh_(c);
        A1w[(rbase + gq*4 + j)*A_STR + w*16 + r] = f2bf(h);
      }
    }
    if (sto >= 0) ((unsigned short*)&S.Ax[0][0][0])[sto] = f2bf(stv);
    __syncthreads();   // B2: new h1 + next-step Ax visible

    // ---- head: only last 24 steps ----
    if (t >= 95){
      const int rown = tid >> 4, cg = tid & 15;
      us8 hv = *(const us8*)&A1w[rown*A_STR + cg*8];
      f32x4 wA0 = *(const f32x4*)&S.Wh2f[cg*8];
      f32x4 wA1 = *(const f32x4*)&S.Wh2f[cg*8 + 4];
      f32x4 wB0 = *(const f32x4*)&S.Wh2f[128 + cg*8];
      f32x4 wB1 = *(const f32x4*)&S.Wh2f[128 + cg*8 + 4];
      float pm = 0.f, ps = 0.f;
      #pragma unroll
      for (int k = 0; k < 4; ++k){
        float h0v = bf2f(hv[k]);     h0v = h0v > 0.f ? h0v : 0.f;
        float h1v = bf2f(hv[4 + k]); h1v = h1v > 0.f ? h1v : 0.f;
        pm = fmaf(h0v, wA0[k], pm);  pm = fmaf(h1v, wA1[k], pm);
        ps = fmaf(h0v, wB0[k], ps);  ps = fmaf(h1v, wB1[k], ps);
      }
      S.red[rown][cg][0] = pm; S.red[rown][cg][1] = ps;
      __syncthreads(); // B3 (uniform: t is uniform)
      if (tid < 64){
        int row = tid >> 1, o = tid & 1;
        float s = S.bh_s[o];
        #pragma unroll
        for (int k = 0; k < 16; ++k) s += S.red[row][k][o];
        if (o) s = (s > 15.f) ? s : __logf(1.0f + __expf(s));
        out[((b*24 + (t - 95))*320 + (n0 + row))*2 + o] = s;
      }
    }
  }
}

extern "C" void kernel_launch(void* const* d_in, const int* in_sizes, int n_in,
                              void* d_out, int out_size, void* d_ws, size_t ws_size,
                              hipStream_t stream) {
  const float* hist = (const float*)d_in[0];
  const float* fut  = (const float*)d_in[1];
  const float* We   = (const float*)d_in[2];
  const float* be   = (const float*)d_in[3];
  const float* Wih0 = (const float*)d_in[4];
  const float* Whh0 = (const float*)d_in[5];
  const float* bih0 = (const float*)d_in[6];
  const float* bhh0 = (const float*)d_in[7];
  const float* Wih1 = (const float*)d_in[8];
  const float* Whh1 = (const float*)d_in[9];
  const float* bih1 = (const float*)d_in[10];
  const float* bhh1 = (const float*)d_in[11];
  const float* Wh   = (const float*)d_in[12];
  const float* bh   = (const float*)d_in[13];
  float* out = (float*)d_out;

  deepar_kernel<<<dim3(160), dim3(512), 0, stream>>>(
      hist, fut, We, be, Wih0, Whh0, bih0, bhh0,
      Wih1, Whh1, bih1, bhh1, Wh, bh, out);
}

// Round 4
// 972.423 us; speedup vs baseline: 1.2990x; 1.2990x over previous
//
#include <hip/hip_runtime.h>

typedef __bf16 bf16x8 __attribute__((ext_vector_type(8)));
typedef unsigned short us8 __attribute__((ext_vector_type(8)));
typedef float f32x4 __attribute__((ext_vector_type(4)));

#define NROW 32      // rows per workgroup (160 WGs x 32 = 5120)
#define A_STR 136    // ushort stride per A row: 16B-aligned, 4-dword bank skew
#define NSTEP 119

__device__ __forceinline__ unsigned short f2bf(float f){
  unsigned int x = __builtin_bit_cast(unsigned int, f);
  x += 0x7fffu + ((x >> 16) & 1u);          // RNE
  return (unsigned short)(x >> 16);
}
__device__ __forceinline__ float bf2f(unsigned short s){
  unsigned int x = ((unsigned int)s) << 16;
  return __builtin_bit_cast(float, x);
}
__device__ __forceinline__ float sigm(float x){ return 1.0f/(1.0f + __expf(-x)); }
__device__ __forceinline__ float tanh_(float x){ float e = __expf(2.0f*x); return 1.0f - 2.0f/(e + 1.0f); }

__device__ __forceinline__ f32x4 MFMA(us8 a, us8 b, f32x4 c){
  return __builtin_amdgcn_mfma_f32_16x16x32_bf16(
      __builtin_bit_cast(bf16x8, a), __builtin_bit_cast(bf16x8, b), c, 0, 0, 0);
}

struct SharedMem {
  unsigned short A0[2][NROW*A_STR];   // h0 state, bf16, double buffered   (17408 B)
  unsigned short A1[2][NROW*A_STR];   // h1 state, bf16, double buffered   (17408 B)
  unsigned short Ax[2][NROW][32];     // x-MFMA A operand                   (4096 B)
  unsigned short xw[512*8];           // x-MFMA B operand per gate-col      (8192 B)
  float c_lds[2][2][512][4];          // c-state, per-lane-contiguous      (32768 B)
  float b1[512];                      // bih1+bhh1 per col                  (2048 B)
  float Wh2f[256];                    // Wh flattened                       (1024 B)
  float red[NROW][16][2];             // head partial sums                  (4096 B)
  float we_s[64];
  float be_s[64];
  float bh_s[2];
};  // ~87.3 KB total -> exactly 1 block/CU -> 2 waves/EU -> 256-reg budget

__global__ __launch_bounds__(512)
__attribute__((amdgpu_waves_per_eu(2, 2)))
void deepar_kernel(
    const float* __restrict__ hist, const float* __restrict__ fut,
    const float* __restrict__ We,   const float* __restrict__ be,
    const float* __restrict__ Wih0, const float* __restrict__ Whh0,
    const float* __restrict__ bih0, const float* __restrict__ bhh0,
    const float* __restrict__ Wih1, const float* __restrict__ Whh1,
    const float* __restrict__ bih1, const float* __restrict__ bhh1,
    const float* __restrict__ Wh,   const float* __restrict__ bh,
    float* __restrict__ out)
{
  __shared__ SharedMem S;
  const int tid = threadIdx.x;
  const int wg  = blockIdx.x;
  const int b   = wg / 10;
  const int n0  = (wg % 10) * NROW;
  const int w   = tid >> 6;        // wave 0..7
  const int l   = tid & 63;
  const int gq  = l >> 4;          // k-group 0..3
  const int r   = l & 15;          // row/col within 16-tile

  // ---------------- prologue: zero + param staging ----------------
  {
    us8 z = {0,0,0,0,0,0,0,0};
    us8* pA0 = (us8*)&S.A0[0][0];
    us8* pA1 = (us8*)&S.A1[0][0];
    for (int i = tid; i < 2*NROW*A_STR/8; i += 512){ pA0[i] = z; pA1[i] = z; }
    us8* pAx = (us8*)&S.Ax[0][0][0];
    for (int i = tid; i < 2*NROW*32/8; i += 512) pAx[i] = z;
    f32x4 zf = {0.f,0.f,0.f,0.f};
    #pragma unroll
    for (int q = 0; q < 4; ++q) *(f32x4*)&S.c_lds[q >> 1][q & 1][tid][0] = zf;
  }
  if (tid < 64)       S.we_s[tid]       = We[tid];
  else if (tid < 128) S.be_s[tid - 64]  = be[tid - 64];
  else if (tid < 384) S.Wh2f[tid - 128] = Wh[tid - 128];
  else if (tid < 386) S.bh_s[tid - 384] = bh[tid - 384];
  __syncthreads();

  // per-col x weights: u = Wih0[:, :64]@We ; v = Wih0[:, :64]@be + bih0 + bhh0
  {
    const float* wr = Wih0 + tid * 68;
    float u = 0.f, v = 0.f;
    #pragma unroll 8
    for (int e = 0; e < 64; ++e){
      float wv = wr[e];
      u = fmaf(wv, S.we_s[e], u);
      v = fmaf(wv, S.be_s[e], v);
    }
    v += bih0[tid] + bhh0[tid];
    unsigned short* xp = &S.xw[tid * 8];
    xp[0] = f2bf(u);
    xp[1] = f2bf(wr[64]); xp[2] = f2bf(wr[65]); xp[3] = f2bf(wr[66]); xp[4] = f2bf(wr[67]);
    xp[5] = f2bf(v);
    xp[6] = 0; xp[7] = 0;
    S.b1[tid] = bih1[tid] + bhh1[tid];
  }
  // Ax constant-one column (k=5), both buffers
  if (tid < 64){ int row = tid >> 1, bsel = tid & 1; S.Ax[bsel][row][5] = 0x3F80; }
  // stage step-0 scalars: tgt tau=0, cov tau=1 -> Ax[0]
  if (tid < 160){
    int srow, sch, tau;
    if (tid < 32){ srow = tid; sch = 0; tau = 0; }
    else { int k = tid - 32; srow = k >> 2; sch = 1 + (k & 3); tau = 1; }
    const float* p = hist + ((b*96 + tau)*320 + n0 + srow)*5;
    S.Ax[0][srow][sch] = f2bf(p[sch]);
  }

  // register-resident recurrent weights: WB[mat][gate][kblock]
  us8 WB[3][4][4];
  #pragma unroll
  for (int m = 0; m < 3; ++m){
    const float* base = (m == 0) ? Whh0 : (m == 1) ? Wih1 : Whh1;
    #pragma unroll
    for (int g = 0; g < 4; ++g){
      int col = g*128 + w*16 + r;
      #pragma unroll
      for (int q = 0; q < 4; ++q){
        const float* p = base + col*128 + q*32 + gq*8;
        f32x4 x0 = *(const f32x4*)p;
        f32x4 x1 = *(const f32x4*)(p + 4);
        us8 tt;
        tt[0]=f2bf(x0[0]); tt[1]=f2bf(x0[1]); tt[2]=f2bf(x0[2]); tt[3]=f2bf(x0[3]);
        tt[4]=f2bf(x1[0]); tt[5]=f2bf(x1[1]); tt[6]=f2bf(x1[2]); tt[7]=f2bf(x1[3]);
        WB[m][g][q] = tt;
      }
    }
  }

  __syncthreads();

  // ---------------- time loop ----------------
  for (int t = 0; t < NSTEP; ++t){
    const int pb = t & 1, nb = pb ^ 1;
    const unsigned short* A0r = S.A0[pb];
    unsigned short*       A0w = S.A0[nb];
    const unsigned short* A1r = S.A1[pb];
    unsigned short*       A1w = S.A1[nb];

    // issue next-step scalar loads FIRST (hide HBM latency under both MFMA phases)
    float stv = 0.f; int sto = -1;
    if (t + 1 < NSTEP && tid < 160){
      int srow, sch, tau;
      if (tid < 32){ srow = tid; sch = 0; tau = t + 1; }
      else { int k = tid - 32; srow = k >> 2; sch = 1 + (k & 3); tau = t + 2; }
      const float* p = (tau < 96) ? (hist + ((b*96 + tau)*320 + n0 + srow)*5)
                                  : (fut  + ((b*24 + (tau - 96))*320 + n0 + srow)*5);
      stv = p[sch];
      sto = nb*NROW*32 + srow*32 + sch;
    }

    // ---- layer 0: gates = x-MFMA + h0 @ Whh0^T ; in-register activations ----
    #pragma unroll
    for (int rt = 0; rt < 2; ++rt){
      const int rbase = rt * 16;
      // hoist c-state read: independent of the MFMAs, latency hidden under them
      f32x4 cprev = *(const f32x4*)&S.c_lds[0][rt][tid][0];
      f32x4 acc[4];
      us8 ax = *(const us8*)&S.Ax[pb][rbase + r][gq*8];
      #pragma unroll
      for (int g = 0; g < 4; ++g){
        us8 bx = *(const us8*)&S.xw[(g*128 + w*16 + r)*8];
        f32x4 z = {0.f,0.f,0.f,0.f};
        acc[g] = MFMA(ax, bx, z);
      }
      #pragma unroll
      for (int q = 0; q < 4; ++q){
        us8 a = *(const us8*)&A0r[(rbase + r)*A_STR + q*32 + gq*8];
        #pragma unroll
        for (int g = 0; g < 4; ++g) acc[g] = MFMA(a, WB[0][g][q], acc[g]);
      }
      f32x4 cnew;
      #pragma unroll
      for (int j = 0; j < 4; ++j){
        float c = fmaf(sigm(acc[1][j]), cprev[j], sigm(acc[0][j]) * tanh_(acc[2][j]));
        cnew[j] = c;
        float h = sigm(acc[3][j]) * tanh_(c);
        A0w[(rbase + gq*4 + j)*A_STR + w*16 + r] = f2bf(h);
      }
      *(f32x4*)&S.c_lds[0][rt][tid][0] = cnew;
    }
    __syncthreads();   // B1: new h0 visible

    // ---- layer 1: gates = b1 + h0new @ Wih1^T + h1 @ Whh1^T ----
    #pragma unroll
    for (int rt = 0; rt < 2; ++rt){
      const int rbase = rt * 16;
      f32x4 cprev = *(const f32x4*)&S.c_lds[1][rt][tid][0];
      float b1v = S.b1[w*16 + r];            // gate 0 bias; others loaded below
      f32x4 acc[4];
      #pragma unroll
      for (int g = 0; g < 4; ++g){
        float bv = S.b1[g*128 + w*16 + r];
        f32x4 iv = {bv, bv, bv, bv};
        acc[g] = iv;
      }
      (void)b1v;
      #pragma unroll
      for (int q = 0; q < 4; ++q){
        us8 a = *(const us8*)&A0w[(rbase + r)*A_STR + q*32 + gq*8];
        #pragma unroll
        for (int g = 0; g < 4; ++g) acc[g] = MFMA(a, WB[1][g][q], acc[g]);
      }
      #pragma unroll
      for (int q = 0; q < 4; ++q){
        us8 a = *(const us8*)&A1r[(rbase + r)*A_STR + q*32 + gq*8];
        #pragma unroll
        for (int g = 0; g < 4; ++g) acc[g] = MFMA(a, WB[2][g][q], acc[g]);
      }
      f32x4 cnew;
      #pragma unroll
      for (int j = 0; j < 4; ++j){
        float c = fmaf(sigm(acc[1][j]), cprev[j], sigm(acc[0][j]) * tanh_(acc[2][j]));
        cnew[j] = c;
        float h = sigm(acc[3][j]) * tanh_(c);
        A1w[(rbase + gq*4 + j)*A_STR + w*16 + r] = f2bf(h);
      }
      *(f32x4*)&S.c_lds[1][rt][tid][0] = cnew;
    }
    if (sto >= 0) ((unsigned short*)&S.Ax[0][0][0])[sto] = f2bf(stv);
    __syncthreads();   // B2: new h1 + next-step Ax visible

    // ---- head: only last 24 steps ----
    if (t >= 95){
      const int rown = tid >> 4, cg = tid & 15;
      us8 hv = *(const us8*)&A1w[rown*A_STR + cg*8];
      f32x4 wA0 = *(const f32x4*)&S.Wh2f[cg*8];
      f32x4 wA1 = *(const f32x4*)&S.Wh2f[cg*8 + 4];
      f32x4 wB0 = *(const f32x4*)&S.Wh2f[128 + cg*8];
      f32x4 wB1 = *(const f32x4*)&S.Wh2f[128 + cg*8 + 4];
      float pm = 0.f, ps = 0.f;
      #pragma unroll
      for (int k = 0; k < 4; ++k){
        float h0v = bf2f(hv[k]);     h0v = h0v > 0.f ? h0v : 0.f;
        float h1v = bf2f(hv[4 + k]); h1v = h1v > 0.f ? h1v : 0.f;
        pm = fmaf(h0v, wA0[k], pm);  pm = fmaf(h1v, wA1[k], pm);
        ps = fmaf(h0v, wB0[k], ps);  ps = fmaf(h1v, wB1[k], ps);
      }
      S.red[rown][cg][0] = pm; S.red[rown][cg][1] = ps;
      __syncthreads(); // B3 (uniform: t is uniform)
      if (tid < 64){
        int row = tid >> 1, o = tid & 1;
        float s = S.bh_s[o];
        #pragma unroll
        for (int k = 0; k < 16; ++k) s += S.red[row][k][o];
        if (o) s = (s > 15.f) ? s : __logf(1.0f + __expf(s));
        out[((b*24 + (t - 95))*320 + (n0 + row))*2 + o] = s;
      }
    }
  }
}

extern "C" void kernel_launch(void* const* d_in, const int* in_sizes, int n_in,
                              void* d_out, int out_size, void* d_ws, size_t ws_size,
                              hipStream_t stream) {
  const float* hist = (const float*)d_in[0];
  const float* fut  = (const float*)d_in[1];
  const float* We   = (const float*)d_in[2];
  const float* be   = (const float*)d_in[3];
  const float* Wih0 = (const float*)d_in[4];
  const float* Whh0 = (const float*)d_in[5];
  const float* bih0 = (const float*)d_in[6];
  const float* bhh0 = (const float*)d_in[7];
  const float* Wih1 = (const float*)d_in[8];
  const float* Whh1 = (const float*)d_in[9];
  const float* bih1 = (const float*)d_in[10];
  const float* bhh1 = (const float*)d_in[11];
  const float* Wh   = (const float*)d_in[12];
  const float* bh   = (const float*)d_in[13];
  float* out = (float*)d_out;

  deepar_kernel<<<dim3(160), dim3(512), 0, stream>>>(
      hist, fut, We, be, Wih0, Whh0, bih0, bhh0,
      Wih1, Whh1, bih1, bhh1, Wh, bh, out);
}